// Round 1
// baseline (188.243 us; speedup 1.0000x reference)
//
#include <hip/hip_runtime.h>

#define WN 4096   // width (nodes per level)
#define BN 256    // batch
#define KN 8      // parents per node
#define NLVL 15   // levels after the prior

// h is stored transposed: h[n*BN + b]. Block = one n, lane = b. All gathers coalesced.
__global__ __launch_bounds__(256) void level_kernel(
    const float* __restrict__ hin, float* __restrict__ hout,
    const float* __restrict__ w,   const float* __restrict__ bias,
    const int* __restrict__ parents, const int* __restrict__ inv) {
  const int n = blockIdx.x;
  const int b = threadIdx.x;
  const int*   p  = parents + n * KN;   // wave-uniform -> scalar loads
  const float* wn = w + n * KN;
  const bool iv = inv[n] != 0;
  float acc = bias[n];
#pragma unroll
  for (int k = 0; k < KN; ++k) {
    float x = hin[p[k] * BN + b];       // coalesced 1KB gather per k
    x = iv ? 1.0f - x : x;
    acc = fmaf(x, wn[k], acc);
  }
  hout[n * BN + b] = fmaxf(acc, 0.0f);
}

// h0[n*BN+b] = relu(obs[b*WN+n]*pw[n]+pb[n]) — LDS-tiled transpose, both sides coalesced
__global__ __launch_bounds__(1024) void init_kernel(
    const float* __restrict__ obs, const float* __restrict__ pw,
    const float* __restrict__ pb, float* __restrict__ h0) {
  __shared__ float tile[32][33];
  const int n = blockIdx.x * 32 + threadIdx.x;
  const int b = blockIdx.y * 32 + threadIdx.y;
  tile[threadIdx.y][threadIdx.x] =
      fmaxf(fmaf(obs[b * WN + n], pw[n], pb[n]), 0.0f);
  __syncthreads();
  const int n2 = blockIdx.x * 32 + threadIdx.y;
  const int b2 = blockIdx.y * 32 + threadIdx.x;
  h0[n2 * BN + b2] = tile[threadIdx.x][threadIdx.y];
}

// d_out[b*WN+n] = src[n*BN+b] — LDS-tiled transpose
__global__ __launch_bounds__(1024) void trans_kernel(
    const float* __restrict__ src, float* __restrict__ dst) {
  __shared__ float tile[32][33];
  const int b = blockIdx.y * 32 + threadIdx.x;
  const int n = blockIdx.x * 32 + threadIdx.y;
  tile[threadIdx.y][threadIdx.x] = src[n * BN + b];
  __syncthreads();
  const int b2 = blockIdx.y * 32 + threadIdx.y;
  const int n2 = blockIdx.x * 32 + threadIdx.x;
  dst[b2 * WN + n2] = tile[threadIdx.x][threadIdx.y];
}

extern "C" void kernel_launch(void* const* d_in, const int* in_sizes, int n_in,
                              void* d_out, int out_size, void* d_ws, size_t ws_size,
                              hipStream_t stream) {
  const float* obs = (const float*)d_in[0];   // (B, W)
  const float* pw  = (const float*)d_in[1];   // (W,)
  const float* pb  = (const float*)d_in[2];   // (W,)
  const float* wts = (const float*)d_in[3];   // (15, W, K)
  const float* bia = (const float*)d_in[4];   // (15, W)
  const int*   par = (const int*)d_in[5];     // (15, W, K)
  const int*   inv = (const int*)d_in[6];     // (15, W)
  float* out  = (float*)d_out;

  // Ping-pong buffers in (W, B) layout. d_out doubles as scratch (fully
  // overwritten by the final transpose); d_ws needs W*B*4 = 4 MB.
  float* bufA = out;            // h0, h2, ..., h14
  float* bufB = (float*)d_ws;   // h1, h3, ..., h15 (final)

  init_kernel<<<dim3(WN / 32, BN / 32), dim3(32, 32), 0, stream>>>(obs, pw, pb, bufA);

  const float* cur = bufA;
  for (int l = 0; l < NLVL; ++l) {
    float* dst = (l & 1) ? bufA : bufB;
    level_kernel<<<WN, BN, 0, stream>>>(cur, dst,
                                        wts + (size_t)l * WN * KN,
                                        bia + (size_t)l * WN,
                                        par + (size_t)l * WN * KN,
                                        inv + (size_t)l * WN);
    cur = dst;
  }
  // cur == bufB (l=14 even -> bufB). Transpose (W,B) -> (B,W) into d_out.
  trans_kernel<<<dim3(WN / 32, BN / 32), dim3(32, 32), 0, stream>>>(cur, out);
}